// Round 13
// baseline (31.664 us; speedup 1.0000x reference)
//
#include <hip/hip_runtime.h>

namespace {
constexpr int Cc   = 32;
constexpr int H    = 128;
constexpr int W    = 128;
constexpr int HWsz = H * W;        // 16384
constexpr int NPIX = 8 * HWsz;     // 131072
constexpr int NROW = NPIX / W;     // 1024 rows -> one wave per row
constexpr int CG   = 4;            // channels per load group (8 groups, dbuf)
}

__device__ inline float2 mk2(float a, float b) { float2 r; r.x = a; r.y = b; return r; }
__device__ inline void fma2(float2& acc, const float2& a, const float2& b) {
    acc.x += a.x * b.x; acc.y += a.y * b.y;
}

// One wave per image row, ALL 32 channels: no LDS exchange, no barriers, no
// idle waves. Channel loop register-double-buffered (load group cg+1 while
// computing cg). XCD swizzle: image = blockIdx&7. Per-lane softmax for 2 px.
__global__ __launch_bounds__(64, 4) void cl_fused_kernel(const float* __restrict__ A,
                                                         const float* __restrict__ B,
                                                         double* __restrict__ partial) {
    int t   = threadIdx.x;           // lane: 2 pixels each
    int blk = blockIdx.x;
    int b   = blk & 7;               // image == XCD
    int h   = blk >> 3;              // row 0..127
    int w0  = t * 2;

    int hc[3];
#pragma unroll
    for (int r = 0; r < 3; ++r) hc[r] = min(max(h + r - 1, 0), H - 1);

    const float* Ap  = A + (size_t)b * Cc * HWsz + h * W + w0;
    const float* Bb  = B + (size_t)b * Cc * HWsz;
    const float* Br0 = Bb + hc[0] * W + w0;
    const float* Br1 = Bb + hc[1] * W + w0;
    const float* Br2 = Bb + hc[2] * W + w0;

    float2 sim[9], bn[3];
#pragma unroll
    for (int k = 0; k < 9; ++k) sim[k] = mk2(0, 0);
#pragma unroll
    for (int r = 0; r < 3; ++r) bn[r] = mk2(0, 0);
    float2 sa2 = mk2(0, 0);

    // register double-buffer: 2 x 4 channels x 4 streams
    float2 a_[2][CG], b0_[2][CG], b1_[2][CG], b2_[2][CG];
#pragma unroll
    for (int c = 0; c < CG; ++c) {
        a_[0][c]  = *(const float2*)(Ap  + c * HWsz);
        b0_[0][c] = *(const float2*)(Br0 + c * HWsz);
        b1_[0][c] = *(const float2*)(Br1 + c * HWsz);
        b2_[0][c] = *(const float2*)(Br2 + c * HWsz);
    }

#pragma unroll
    for (int cg = 0; cg < 8; ++cg) {
        const int cur = cg & 1, nxt = cur ^ 1;
        if (cg < 7) {
            const int cb = (cg + 1) * CG;
#pragma unroll
            for (int c = 0; c < CG; ++c) {
                a_[nxt][c]  = *(const float2*)(Ap  + (cb + c) * HWsz);
                b0_[nxt][c] = *(const float2*)(Br0 + (cb + c) * HWsz);
                b1_[nxt][c] = *(const float2*)(Br1 + (cb + c) * HWsz);
                b2_[nxt][c] = *(const float2*)(Br2 + (cb + c) * HWsz);
            }
        }
#pragma unroll
        for (int c = 0; c < CG; ++c) {
            float2 a2 = a_[cur][c], b0 = b0_[cur][c], b1 = b1_[cur][c], b2 = b2_[cur][c];
            float l0 = __shfl_up(b0.y, 1, 64), r0 = __shfl_down(b0.x, 1, 64);
            float l1 = __shfl_up(b1.y, 1, 64), r1 = __shfl_down(b1.x, 1, 64);
            float l2 = __shfl_up(b2.y, 1, 64), r2 = __shfl_down(b2.x, 1, 64);
            fma2(sa2, a2, a2);
            fma2(bn[0], b0, b0);
            fma2(bn[1], b1, b1);
            fma2(bn[2], b2, b2);
            fma2(sim[0], a2, mk2(l0, b0.x));
            fma2(sim[1], a2, b0);
            fma2(sim[2], a2, mk2(b0.y, r0));
            fma2(sim[3], a2, mk2(l1, b1.x));
            fma2(sim[4], a2, b1);
            fma2(sim[5], a2, mk2(b1.y, r1));
            fma2(sim[6], a2, mk2(l2, b2.x));
            fma2(sim[7], a2, b2);
            fma2(sim[8], a2, mk2(b2.y, r2));
        }
    }

    // ---- per-lane epilogue (2 px each), no LDS needed ----
    float2 rn[3]; float rlf[3], rrt[3];
#pragma unroll
    for (int r = 0; r < 3; ++r) {
        rn[r].x = 1.0f / fmaxf(sqrtf(bn[r].x), 1e-12f);
        rn[r].y = 1.0f / fmaxf(sqrtf(bn[r].y), 1e-12f);
        rlf[r] = __shfl_up(rn[r].y, 1, 64);
        rrt[r] = __shfl_down(rn[r].x, 1, 64);
    }

    float accf = 0.f;
#pragma unroll
    for (int j = 0; j < 2; ++j) {
        float ra = 1.0f / fmaxf(sqrtf(j == 0 ? sa2.x : sa2.y), 1e-12f);
        float lg[9], sv[9];
#pragma unroll
        for (int r = 0; r < 3; ++r) {
            bool vr_ = ((unsigned)(h + r - 1) < (unsigned)H);   // block-uniform
            float nl = (j == 0) ? rlf[r]  : rn[r].x;
            float nm = (j == 0) ? rn[r].x : rn[r].y;
            float nr = (j == 0) ? rn[r].y : rrt[r];
            bool vl  = vr_ && (j == 1 || t > 0);
            bool vrg = vr_ && (j == 0 || t < 63);
            float s0v = (j == 0) ? sim[r * 3 + 0].x : sim[r * 3 + 0].y;
            float s1v = (j == 0) ? sim[r * 3 + 1].x : sim[r * 3 + 1].y;
            float s2v = (j == 0) ? sim[r * 3 + 2].x : sim[r * 3 + 2].y;
            float s0 = vl  ? s0v * ra * nl : 0.f;
            float s1 = vr_ ? s1v * ra * nm : 0.f;
            float s2 = vrg ? s2v * ra * nr : 0.f;
            sv[r * 3 + 0] = s0; lg[r * 3 + 0] = s0 / 0.07f;
            sv[r * 3 + 1] = s1; lg[r * 3 + 1] = s1 / 0.07f;
            sv[r * 3 + 2] = s2; lg[r * 3 + 2] = s2 / 0.07f;
        }
        float m = -1e30f;
#pragma unroll
        for (int k = 0; k < 9; ++k) m = fmaxf(m, lg[k]);
        float Z = 0.f;
#pragma unroll
        for (int k = 0; k < 9; ++k) Z += expf(lg[k] - m);
        float lZ = logf(Z);
#pragma unroll
        for (int k = 0; k < 9; ++k)
            if (sv[k] > 0.5f) accf += (m + lZ - lg[k]);
    }

    double acc = (double)accf;
#pragma unroll
    for (int s = 32; s > 0; s >>= 1) acc += __shfl_down(acc, s, 64);
    if (t == 0) partial[blk] = acc;
}

__global__ __launch_bounds__(256) void cl_final_kernel(const double* __restrict__ partial,
                                                       float* __restrict__ out) {
    __shared__ double sd[256];
    double acc = 0.0;
    for (int i = threadIdx.x; i < NROW; i += 256) acc += partial[i];
    sd[threadIdx.x] = acc;
    __syncthreads();
    for (int s = 128; s > 0; s >>= 1) {
        if (threadIdx.x < s) sd[threadIdx.x] += sd[threadIdx.x + s];
        __syncthreads();
    }
    if (threadIdx.x == 0) out[0] = (float)(sd[0] / (double)NPIX);
}

extern "C" void kernel_launch(void* const* d_in, const int* in_sizes, int n_in,
                              void* d_out, int out_size, void* d_ws, size_t ws_size,
                              hipStream_t stream) {
    const float* A = (const float*)d_in[0];
    const float* B = (const float*)d_in[1];
    float* out = (float*)d_out;

    double* partial = (double*)d_ws;   // 1024 * 8 = 8 KiB

    cl_fused_kernel<<<NROW, 64, 0, stream>>>(A, B, partial);
    cl_final_kernel<<<1, 256, 0, stream>>>(partial, out);
}

// Round 14
// 29.061 us; speedup vs baseline: 1.0896x; 1.0896x over previous
//
#include <hip/hip_runtime.h>

namespace {
constexpr int Cc   = 32;
constexpr int H    = 128;
constexpr int W    = 128;
constexpr int HWsz = H * W;        // 16384
constexpr int NPIX = 8 * HWsz;     // 131072
constexpr int NROW = NPIX / W;     // 1024 rows -> one block per row
constexpr int CPG  = 8;            // channels per group (4 groups = 4 waves)
}

__device__ inline float2 mk2(float a, float b) { float2 r; r.x = a; r.y = b; return r; }
__device__ inline void fma2(float2& acc, const float2& a, const float2& b) {
    acc.x += a.x * b.x; acc.y += a.y * b.y;
}
__device__ inline void add2(float2& acc, const float2& v) { acc.x += v.x; acc.y += v.y; }

// Fused: per-pixel sim[9] + ||A|| + neighbor ||B|| + softmax-CE, one row per block.
// XCD swizzle (image = blockIdx&7) keeps each image's 4.2MB slice in one XCD L2.
// Finish: one atomicAdd(float) per block onto pre-zeroed d_out (no final kernel,
// no fences). Output magnitude ~1e-3 -> atomic-order fp noise << 1.8e-5 threshold.
__global__ __launch_bounds__(256) void cl_fused_kernel(const float* __restrict__ A,
                                                       const float* __restrict__ B,
                                                       float* __restrict__ out) {
    __shared__ float2 ls[13][192];   // sim[9], bn[3], sa — lane-consecutive

    int t   = threadIdx.x & 63;      // lane: 2 pixels each
    int g   = threadIdx.x >> 6;      // channel group == wave id
    int blk = blockIdx.x;
    int b   = blk & 7;               // image == XCD
    int h   = blk >> 3;              // row 0..127
    int w0  = t * 2;

    int hc[3];
#pragma unroll
    for (int r = 0; r < 3; ++r) hc[r] = min(max(h + r - 1, 0), H - 1);

    const float* Ap  = A + (size_t)b * Cc * HWsz + (size_t)g * CPG * HWsz + h * W + w0;
    const float* Bg  = B + (size_t)b * Cc * HWsz + (size_t)g * CPG * HWsz;
    const float* Br0 = Bg + hc[0] * W + w0;
    const float* Br1 = Bg + hc[1] * W + w0;
    const float* Br2 = Bg + hc[2] * W + w0;

    float2 sim[9], bn[3];
#pragma unroll
    for (int k = 0; k < 9; ++k) sim[k] = mk2(0, 0);
#pragma unroll
    for (int r = 0; r < 3; ++r) bn[r] = mk2(0, 0);
    float2 sa2 = mk2(0, 0);

#pragma unroll
    for (int c = 0; c < CPG; ++c) {
        float2 a2 = *(const float2*)(Ap  + c * HWsz);
        float2 b0 = *(const float2*)(Br0 + c * HWsz);
        float2 b1 = *(const float2*)(Br1 + c * HWsz);
        float2 b2 = *(const float2*)(Br2 + c * HWsz);
        float l0 = __shfl_up(b0.y, 1, 64), r0 = __shfl_down(b0.x, 1, 64);
        float l1 = __shfl_up(b1.y, 1, 64), r1 = __shfl_down(b1.x, 1, 64);
        float l2 = __shfl_up(b2.y, 1, 64), r2 = __shfl_down(b2.x, 1, 64);
        fma2(sa2, a2, a2);
        fma2(bn[0], b0, b0);
        fma2(bn[1], b1, b1);
        fma2(bn[2], b2, b2);
        fma2(sim[0], a2, mk2(l0, b0.x));
        fma2(sim[1], a2, b0);
        fma2(sim[2], a2, mk2(b0.y, r0));
        fma2(sim[3], a2, mk2(l1, b1.x));
        fma2(sim[4], a2, b1);
        fma2(sim[5], a2, mk2(b1.y, r1));
        fma2(sim[6], a2, mk2(l2, b2.x));
        fma2(sim[7], a2, b2);
        fma2(sim[8], a2, mk2(b2.y, r2));
    }

    if (g != 0) {
        int idx = (g - 1) * 64 + t;
#pragma unroll
        for (int k = 0; k < 9; ++k) ls[k][idx] = sim[k];
        ls[9][idx]  = bn[0];
        ls[10][idx] = bn[1];
        ls[11][idx] = bn[2];
        ls[12][idx] = sa2;
    }
    __syncthreads();

    if (g == 0) {
#pragma unroll
        for (int gg = 0; gg < 3; ++gg) {
            int idx = gg * 64 + t;
#pragma unroll
            for (int k = 0; k < 9; ++k) add2(sim[k], ls[k][idx]);
            add2(bn[0], ls[9][idx]);
            add2(bn[1], ls[10][idx]);
            add2(bn[2], ls[11][idx]);
            add2(sa2,   ls[12][idx]);
        }

        float2 rn[3]; float rlf[3], rrt[3];
#pragma unroll
        for (int r = 0; r < 3; ++r) {
            rn[r].x = 1.0f / fmaxf(sqrtf(bn[r].x), 1e-12f);
            rn[r].y = 1.0f / fmaxf(sqrtf(bn[r].y), 1e-12f);
            rlf[r] = __shfl_up(rn[r].y, 1, 64);
            rrt[r] = __shfl_down(rn[r].x, 1, 64);
        }

        float accf = 0.f;
#pragma unroll
        for (int j = 0; j < 2; ++j) {
            float ra = 1.0f / fmaxf(sqrtf(j == 0 ? sa2.x : sa2.y), 1e-12f);
            float lg[9], sv[9];
#pragma unroll
            for (int r = 0; r < 3; ++r) {
                bool vr_ = ((unsigned)(h + r - 1) < (unsigned)H);   // block-uniform
                float nl = (j == 0) ? rlf[r]  : rn[r].x;
                float nm = (j == 0) ? rn[r].x : rn[r].y;
                float nr = (j == 0) ? rn[r].y : rrt[r];
                bool vl  = vr_ && (j == 1 || t > 0);
                bool vrg = vr_ && (j == 0 || t < 63);
                float s0v = (j == 0) ? sim[r * 3 + 0].x : sim[r * 3 + 0].y;
                float s1v = (j == 0) ? sim[r * 3 + 1].x : sim[r * 3 + 1].y;
                float s2v = (j == 0) ? sim[r * 3 + 2].x : sim[r * 3 + 2].y;
                float s0 = vl  ? s0v * ra * nl : 0.f;
                float s1 = vr_ ? s1v * ra * nm : 0.f;
                float s2 = vrg ? s2v * ra * nr : 0.f;
                sv[r * 3 + 0] = s0; lg[r * 3 + 0] = s0 / 0.07f;
                sv[r * 3 + 1] = s1; lg[r * 3 + 1] = s1 / 0.07f;
                sv[r * 3 + 2] = s2; lg[r * 3 + 2] = s2 / 0.07f;
            }
            float m = -1e30f;
#pragma unroll
            for (int k = 0; k < 9; ++k) m = fmaxf(m, lg[k]);
            float Z = 0.f;
#pragma unroll
            for (int k = 0; k < 9; ++k) Z += expf(lg[k] - m);
            float lZ = logf(Z);
#pragma unroll
            for (int k = 0; k < 9; ++k)
                if (sv[k] > 0.5f) accf += (m + lZ - lg[k]);
        }

        double acc = (double)accf;
#pragma unroll
        for (int s = 32; s > 0; s >>= 1) acc += __shfl_down(acc, s, 64);
        if (t == 0) atomicAdd(out, (float)(acc / (double)NPIX));
    }
}

extern "C" void kernel_launch(void* const* d_in, const int* in_sizes, int n_in,
                              void* d_out, int out_size, void* d_ws, size_t ws_size,
                              hipStream_t stream) {
    const float* A = (const float*)d_in[0];
    const float* B = (const float*)d_in[1];
    float* out = (float*)d_out;

    hipMemsetAsync(out, 0, sizeof(float), stream);
    cl_fused_kernel<<<NROW, 256, 0, stream>>>(A, B, out);
}

// Round 15
// 25.526 us; speedup vs baseline: 1.2405x; 1.1385x over previous
//
#include <hip/hip_runtime.h>

namespace {
constexpr int Cc   = 32;
constexpr int H    = 128;
constexpr int W    = 128;
constexpr int HWsz = H * W;        // 16384
constexpr int NPIX = 8 * HWsz;     // 131072
constexpr int NROW = NPIX / W;     // 1024 rows -> one block per row
constexpr int CPG  = 8;            // channels per group (4 groups = 4 waves)
}

__device__ inline float2 mk2(float a, float b) { float2 r; r.x = a; r.y = b; return r; }
__device__ inline void fma2(float2& acc, const float2& a, const float2& b) {
    acc.x += a.x * b.x; acc.y += a.y * b.y;
}
__device__ inline void add2(float2& acc, const float2& v) { acc.x += v.x; acc.y += v.y; }

// Fused: per-pixel sim[9] + ||A|| + neighbor ||B|| + softmax-CE, one row per block.
// XCD swizzle (image = blockIdx&7) keeps each image's 4.2MB slice in one XCD L2.
// (256,8): LDS is 19.9KB -> 8 blocks/CU fit exactly -> 32 waves/CU, VGPR cap 64
// (kernel uses ~48-64, no R6-style squeeze).
__global__ __launch_bounds__(256, 8) void cl_fused_kernel(const float* __restrict__ A,
                                                          const float* __restrict__ B,
                                                          double* __restrict__ partial) {
    __shared__ float2 ls[13][192];   // sim[9], bn[3], sa — lane-consecutive (~19.9KB)

    int t   = threadIdx.x & 63;      // lane: 2 pixels each
    int g   = threadIdx.x >> 6;      // channel group == wave id
    int blk = blockIdx.x;
    int b   = blk & 7;               // image == XCD
    int h   = blk >> 3;              // row 0..127
    int w0  = t * 2;

    int hc[3];
#pragma unroll
    for (int r = 0; r < 3; ++r) hc[r] = min(max(h + r - 1, 0), H - 1);

    const float* Ap  = A + (size_t)b * Cc * HWsz + (size_t)g * CPG * HWsz + h * W + w0;
    const float* Bg  = B + (size_t)b * Cc * HWsz + (size_t)g * CPG * HWsz;
    const float* Br0 = Bg + hc[0] * W + w0;
    const float* Br1 = Bg + hc[1] * W + w0;
    const float* Br2 = Bg + hc[2] * W + w0;

    float2 sim[9], bn[3];
#pragma unroll
    for (int k = 0; k < 9; ++k) sim[k] = mk2(0, 0);
#pragma unroll
    for (int r = 0; r < 3; ++r) bn[r] = mk2(0, 0);
    float2 sa2 = mk2(0, 0);

#pragma unroll
    for (int c = 0; c < CPG; ++c) {
        float2 a2 = *(const float2*)(Ap  + c * HWsz);
        float2 b0 = *(const float2*)(Br0 + c * HWsz);
        float2 b1 = *(const float2*)(Br1 + c * HWsz);
        float2 b2 = *(const float2*)(Br2 + c * HWsz);
        float l0 = __shfl_up(b0.y, 1, 64), r0 = __shfl_down(b0.x, 1, 64);
        float l1 = __shfl_up(b1.y, 1, 64), r1 = __shfl_down(b1.x, 1, 64);
        float l2 = __shfl_up(b2.y, 1, 64), r2 = __shfl_down(b2.x, 1, 64);
        fma2(sa2, a2, a2);
        fma2(bn[0], b0, b0);
        fma2(bn[1], b1, b1);
        fma2(bn[2], b2, b2);
        fma2(sim[0], a2, mk2(l0, b0.x));
        fma2(sim[1], a2, b0);
        fma2(sim[2], a2, mk2(b0.y, r0));
        fma2(sim[3], a2, mk2(l1, b1.x));
        fma2(sim[4], a2, b1);
        fma2(sim[5], a2, mk2(b1.y, r1));
        fma2(sim[6], a2, mk2(l2, b2.x));
        fma2(sim[7], a2, b2);
        fma2(sim[8], a2, mk2(b2.y, r2));
    }

    if (g != 0) {
        int idx = (g - 1) * 64 + t;
#pragma unroll
        for (int k = 0; k < 9; ++k) ls[k][idx] = sim[k];
        ls[9][idx]  = bn[0];
        ls[10][idx] = bn[1];
        ls[11][idx] = bn[2];
        ls[12][idx] = sa2;
    }
    __syncthreads();

    if (g == 0) {
#pragma unroll
        for (int gg = 0; gg < 3; ++gg) {
            int idx = gg * 64 + t;
#pragma unroll
            for (int k = 0; k < 9; ++k) add2(sim[k], ls[k][idx]);
            add2(bn[0], ls[9][idx]);
            add2(bn[1], ls[10][idx]);
            add2(bn[2], ls[11][idx]);
            add2(sa2,   ls[12][idx]);
        }

        float2 rn[3]; float rlf[3], rrt[3];
#pragma unroll
        for (int r = 0; r < 3; ++r) {
            rn[r].x = 1.0f / fmaxf(sqrtf(bn[r].x), 1e-12f);
            rn[r].y = 1.0f / fmaxf(sqrtf(bn[r].y), 1e-12f);
            rlf[r] = __shfl_up(rn[r].y, 1, 64);
            rrt[r] = __shfl_down(rn[r].x, 1, 64);
        }

        float accf = 0.f;
#pragma unroll
        for (int j = 0; j < 2; ++j) {
            float ra = 1.0f / fmaxf(sqrtf(j == 0 ? sa2.x : sa2.y), 1e-12f);
            float lg[9], sv[9];
#pragma unroll
            for (int r = 0; r < 3; ++r) {
                bool vr_ = ((unsigned)(h + r - 1) < (unsigned)H);   // block-uniform
                float nl = (j == 0) ? rlf[r]  : rn[r].x;
                float nm = (j == 0) ? rn[r].x : rn[r].y;
                float nr = (j == 0) ? rn[r].y : rrt[r];
                bool vl  = vr_ && (j == 1 || t > 0);
                bool vrg = vr_ && (j == 0 || t < 63);
                float s0v = (j == 0) ? sim[r * 3 + 0].x : sim[r * 3 + 0].y;
                float s1v = (j == 0) ? sim[r * 3 + 1].x : sim[r * 3 + 1].y;
                float s2v = (j == 0) ? sim[r * 3 + 2].x : sim[r * 3 + 2].y;
                float s0 = vl  ? s0v * ra * nl : 0.f;
                float s1 = vr_ ? s1v * ra * nm : 0.f;
                float s2 = vrg ? s2v * ra * nr : 0.f;
                sv[r * 3 + 0] = s0; lg[r * 3 + 0] = s0 / 0.07f;
                sv[r * 3 + 1] = s1; lg[r * 3 + 1] = s1 / 0.07f;
                sv[r * 3 + 2] = s2; lg[r * 3 + 2] = s2 / 0.07f;
            }
            float m = -1e30f;
#pragma unroll
            for (int k = 0; k < 9; ++k) m = fmaxf(m, lg[k]);
            float Z = 0.f;
#pragma unroll
            for (int k = 0; k < 9; ++k) Z += expf(lg[k] - m);
            float lZ = logf(Z);
#pragma unroll
            for (int k = 0; k < 9; ++k)
                if (sv[k] > 0.5f) accf += (m + lZ - lg[k]);
        }

        double acc = (double)accf;
#pragma unroll
        for (int s = 32; s > 0; s >>= 1) acc += __shfl_down(acc, s, 64);
        if (t == 0) partial[blk] = acc;
    }
}

__global__ __launch_bounds__(256) void cl_final_kernel(const double* __restrict__ partial,
                                                       float* __restrict__ out) {
    __shared__ double sd[256];
    double acc = 0.0;
    for (int i = threadIdx.x; i < NROW; i += 256) acc += partial[i];
    sd[threadIdx.x] = acc;
    __syncthreads();
    for (int s = 128; s > 0; s >>= 1) {
        if (threadIdx.x < s) sd[threadIdx.x] += sd[threadIdx.x + s];
        __syncthreads();
    }
    if (threadIdx.x == 0) out[0] = (float)(sd[0] / (double)NPIX);
}

extern "C" void kernel_launch(void* const* d_in, const int* in_sizes, int n_in,
                              void* d_out, int out_size, void* d_ws, size_t ws_size,
                              hipStream_t stream) {
    const float* A = (const float*)d_in[0];
    const float* B = (const float*)d_in[1];
    float* out = (float*)d_out;

    double* partial = (double*)d_ws;   // 1024 * 8 = 8 KiB

    cl_fused_kernel<<<NROW, 256, 0, stream>>>(A, B, partial);
    cl_final_kernel<<<1, 256, 0, stream>>>(partial, out);
}

// Round 16
// 16.770 us; speedup vs baseline: 1.8881x; 1.5221x over previous
//
#include <hip/hip_runtime.h>

namespace {
constexpr int Cc   = 32;
constexpr int H    = 128;
constexpr int W    = 128;
constexpr int HWsz = H * W;        // 16384
constexpr int NPIX = 8 * HWsz;     // 131072
constexpr int NROW = NPIX / W;     // 1024 rows -> one block per row
constexpr int CPG  = 8;            // channels per group (4 groups = 4 waves)
}

__device__ inline float2 mk2(float a, float b) { float2 r; r.x = a; r.y = b; return r; }
__device__ inline void fma2(float2& acc, const float2& a, const float2& b) {
    acc.x += a.x * b.x; acc.y += a.y * b.y;
}
__device__ inline void add2(float2& acc, const float2& v) { acc.x += v.x; acc.y += v.y; }

// Fused: per-pixel sim[9] + ||A|| + neighbor ||B|| + softmax-CE, one row per block.
// XCD swizzle (image = blockIdx&7). Full 32-load hoist pinned with asm keep-alive
// (R12) at R8's occupancy: (256,4) -> VGPR cap 128 -> 4 blocks/CU = 16 waves/CU.
__global__ __launch_bounds__(256, 4) void cl_fused_kernel(const float* __restrict__ A,
                                                          const float* __restrict__ B,
                                                          double* __restrict__ partial) {
    __shared__ float2 ls[13][192];   // sim[9], bn[3], sa — lane-consecutive

    int t   = threadIdx.x & 63;      // lane: 2 pixels each
    int g   = threadIdx.x >> 6;      // channel group == wave id
    int blk = blockIdx.x;
    int b   = blk & 7;               // image == XCD
    int h   = blk >> 3;              // row 0..127
    int w0  = t * 2;

    int hc[3];
#pragma unroll
    for (int r = 0; r < 3; ++r) hc[r] = min(max(h + r - 1, 0), H - 1);

    const float* Ap  = A + (size_t)b * Cc * HWsz + (size_t)g * CPG * HWsz + h * W + w0;
    const float* Bg  = B + (size_t)b * Cc * HWsz + (size_t)g * CPG * HWsz;
    const float* Br0 = Bg + hc[0] * W + w0;
    const float* Br1 = Bg + hc[1] * W + w0;
    const float* Br2 = Bg + hc[2] * W + w0;

    // ---- issue ALL 32 loads, pin them resident (single latency exposure) ----
    float2 av[CPG], b0v[CPG], b1v[CPG], b2v[CPG];
#pragma unroll
    for (int c = 0; c < CPG; ++c) {
        av[c]  = *(const float2*)(Ap  + c * HWsz);
        b0v[c] = *(const float2*)(Br0 + c * HWsz);
        b1v[c] = *(const float2*)(Br1 + c * HWsz);
        b2v[c] = *(const float2*)(Br2 + c * HWsz);
    }
#pragma unroll
    for (int c = 0; c < CPG; ++c) {
        asm volatile("" : "+v"(av[c]), "+v"(b0v[c]), "+v"(b1v[c]), "+v"(b2v[c])
                     :: "memory");
    }

    float2 sim[9], bn[3];
#pragma unroll
    for (int k = 0; k < 9; ++k) sim[k] = mk2(0, 0);
#pragma unroll
    for (int r = 0; r < 3; ++r) bn[r] = mk2(0, 0);
    float2 sa2 = mk2(0, 0);

#pragma unroll
    for (int c = 0; c < CPG; ++c) {
        float2 a2 = av[c], b0 = b0v[c], b1 = b1v[c], b2 = b2v[c];
        float l0 = __shfl_up(b0.y, 1, 64), r0 = __shfl_down(b0.x, 1, 64);
        float l1 = __shfl_up(b1.y, 1, 64), r1 = __shfl_down(b1.x, 1, 64);
        float l2 = __shfl_up(b2.y, 1, 64), r2 = __shfl_down(b2.x, 1, 64);
        fma2(sa2, a2, a2);
        fma2(bn[0], b0, b0);
        fma2(bn[1], b1, b1);
        fma2(bn[2], b2, b2);
        fma2(sim[0], a2, mk2(l0, b0.x));
        fma2(sim[1], a2, b0);
        fma2(sim[2], a2, mk2(b0.y, r0));
        fma2(sim[3], a2, mk2(l1, b1.x));
        fma2(sim[4], a2, b1);
        fma2(sim[5], a2, mk2(b1.y, r1));
        fma2(sim[6], a2, mk2(l2, b2.x));
        fma2(sim[7], a2, b2);
        fma2(sim[8], a2, mk2(b2.y, r2));
    }

    if (g != 0) {
        int idx = (g - 1) * 64 + t;
#pragma unroll
        for (int k = 0; k < 9; ++k) ls[k][idx] = sim[k];
        ls[9][idx]  = bn[0];
        ls[10][idx] = bn[1];
        ls[11][idx] = bn[2];
        ls[12][idx] = sa2;
    }
    __syncthreads();

    if (g == 0) {
#pragma unroll
        for (int gg = 0; gg < 3; ++gg) {
            int idx = gg * 64 + t;
#pragma unroll
            for (int k = 0; k < 9; ++k) add2(sim[k], ls[k][idx]);
            add2(bn[0], ls[9][idx]);
            add2(bn[1], ls[10][idx]);
            add2(bn[2], ls[11][idx]);
            add2(sa2,   ls[12][idx]);
        }

        float2 rn[3]; float rlf[3], rrt[3];
#pragma unroll
        for (int r = 0; r < 3; ++r) {
            rn[r].x = 1.0f / fmaxf(sqrtf(bn[r].x), 1e-12f);
            rn[r].y = 1.0f / fmaxf(sqrtf(bn[r].y), 1e-12f);
            rlf[r] = __shfl_up(rn[r].y, 1, 64);
            rrt[r] = __shfl_down(rn[r].x, 1, 64);
        }

        float accf = 0.f;
#pragma unroll
        for (int j = 0; j < 2; ++j) {
            float ra = 1.0f / fmaxf(sqrtf(j == 0 ? sa2.x : sa2.y), 1e-12f);
            float lg[9], sv[9];
#pragma unroll
            for (int r = 0; r < 3; ++r) {
                bool vr_ = ((unsigned)(h + r - 1) < (unsigned)H);   // block-uniform
                float nl = (j == 0) ? rlf[r]  : rn[r].x;
                float nm = (j == 0) ? rn[r].x : rn[r].y;
                float nr = (j == 0) ? rn[r].y : rrt[r];
                bool vl  = vr_ && (j == 1 || t > 0);
                bool vrg = vr_ && (j == 0 || t < 63);
                float s0v = (j == 0) ? sim[r * 3 + 0].x : sim[r * 3 + 0].y;
                float s1v = (j == 0) ? sim[r * 3 + 1].x : sim[r * 3 + 1].y;
                float s2v = (j == 0) ? sim[r * 3 + 2].x : sim[r * 3 + 2].y;
                float s0 = vl  ? s0v * ra * nl : 0.f;
                float s1 = vr_ ? s1v * ra * nm : 0.f;
                float s2 = vrg ? s2v * ra * nr : 0.f;
                sv[r * 3 + 0] = s0; lg[r * 3 + 0] = s0 / 0.07f;
                sv[r * 3 + 1] = s1; lg[r * 3 + 1] = s1 / 0.07f;
                sv[r * 3 + 2] = s2; lg[r * 3 + 2] = s2 / 0.07f;
            }
            float m = -1e30f;
#pragma unroll
            for (int k = 0; k < 9; ++k) m = fmaxf(m, lg[k]);
            float Z = 0.f;
#pragma unroll
            for (int k = 0; k < 9; ++k) Z += expf(lg[k] - m);
            float lZ = logf(Z);
#pragma unroll
            for (int k = 0; k < 9; ++k)
                if (sv[k] > 0.5f) accf += (m + lZ - lg[k]);
        }

        double acc = (double)accf;
#pragma unroll
        for (int s = 32; s > 0; s >>= 1) acc += __shfl_down(acc, s, 64);
        if (t == 0) partial[blk] = acc;
    }
}

__global__ __launch_bounds__(256) void cl_final_kernel(const double* __restrict__ partial,
                                                       float* __restrict__ out) {
    __shared__ double sd[256];
    double acc = 0.0;
    for (int i = threadIdx.x; i < NROW; i += 256) acc += partial[i];
    sd[threadIdx.x] = acc;
    __syncthreads();
    for (int s = 128; s > 0; s >>= 1) {
        if (threadIdx.x < s) sd[threadIdx.x] += sd[threadIdx.x + s];
        __syncthreads();
    }
    if (threadIdx.x == 0) out[0] = (float)(sd[0] / (double)NPIX);
}

extern "C" void kernel_launch(void* const* d_in, const int* in_sizes, int n_in,
                              void* d_out, int out_size, void* d_ws, size_t ws_size,
                              hipStream_t stream) {
    const float* A = (const float*)d_in[0];
    const float* B = (const float*)d_in[1];
    float* out = (float*)d_out;

    double* partial = (double*)d_ws;   // 1024 * 8 = 8 KiB

    cl_fused_kernel<<<NROW, 256, 0, stream>>>(A, B, partial);
    cl_final_kernel<<<1, 256, 0, stream>>>(partial, out);
}